// Round 2
// baseline (999.809 us; speedup 1.0000x reference)
//
#include <hip/hip_runtime.h>
#include <math.h>

// ---------------------------------------------------------------------------
// Invariant Point Attention (AF2-style), B=1, N=768, C1=384, C2=128, H=12,
// SQK=SV=16, PQK=4, PV=8.  f32, flash-style fused attention (single rep pass).
// ---------------------------------------------------------------------------

namespace {
constexpr int NRES = 768;
constexpr int C1V  = 384;

// workspace layout (float offsets)
constexpr size_t OFF_R     = 0;         // [768][12]  rotation (9 used)
constexpr size_t OFF_T     = 10240;     // [768][4]   translation (3 used)
constexpr size_t OFF_PW    = 13824;     // [16]       head point weights
constexpr size_t OFF_W2DT  = 13952;     // [12][128]  w2d transposed
constexpr size_t OFF_WPACK = 16384;     // [384][1152] packed proj weights
constexpr size_t OFF_BPACK = 458752;    // [1152]     packed proj bias
constexpr size_t OFF_PROJ  = 460800;    // [768][1152] proj result:
                                        //   +0 qs(192) | +192 kv(384) | +576 qp(144) | +720 kvp(432)
constexpr size_t OFF_QPT   = 1345536;   // [768][12][4][3]  q points (global frame)
constexpr size_t OFF_KPT   = 1456128;   // [768][12][4][3]  k points (global frame)
constexpr size_t OFF_VPTT  = 1566720;   // [12*8*3][768]    v points transposed
constexpr size_t OFF_VST   = 1787904;   // [12*16][768]     v scalar transposed
constexpr size_t OFF_FA    = 1935360;   // [768][2112] final_act
constexpr size_t OFF_PART  = 3557376;   // [4][768][384] split-K partials
}

// ---------------- K0: rotations, translations, pw, w2d transpose ------------
__global__ void k0_prep(const float* __restrict__ recT,
                        const float* __restrict__ tw,
                        const float* __restrict__ w2d,
                        float* __restrict__ ws) {
  int gid = blockIdx.x * 256 + threadIdx.x;
  if (gid < NRES) {
    float w = recT[gid*7+0], x = recT[gid*7+1], y = recT[gid*7+2], z = recT[gid*7+3];
    float inv = rsqrtf(w*w + x*x + y*y + z*z);
    w *= inv; x *= inv; y *= inv; z *= inv;
    float* r = ws + OFF_R + (size_t)gid*12;
    r[0] = 1.f-2.f*(y*y+z*z); r[1] = 2.f*(x*y-w*z);     r[2] = 2.f*(x*z+w*y);
    r[3] = 2.f*(x*y+w*z);     r[4] = 1.f-2.f*(x*x+z*z); r[5] = 2.f*(y*z-w*x);
    r[6] = 2.f*(x*z-w*y);     r[7] = 2.f*(y*z+w*x);     r[8] = 1.f-2.f*(x*x+y*y);
    float* tv = ws + OFF_T + (size_t)gid*4;
    tv[0] = recT[gid*7+4]; tv[1] = recT[gid*7+5]; tv[2] = recT[gid*7+6]; tv[3] = 0.f;
  } else if (gid < NRES + 12) {
    int h = gid - NRES;
    (ws + OFF_PW)[h] = sqrtf(1.f/54.f) * log1pf(expf(tw[h]));   // pw*softplus
  } else if (gid < NRES + 12 + 1536) {
    int idx = gid - NRES - 12;
    int h = idx % 12, c = idx / 12;
    (ws + OFF_W2DT)[h*128 + c] = w2d[c*12 + h];
  }
}

// ---------------- K0b: pack the 4 weight matrices + biases ------------------
__global__ void k0b_pack(const float* __restrict__ qw,  const float* __restrict__ qb,
                         const float* __restrict__ kvw, const float* __restrict__ kvb,
                         const float* __restrict__ qpw, const float* __restrict__ qpb,
                         const float* __restrict__ kvpw,const float* __restrict__ kvpb,
                         float* __restrict__ ws) {
  int idx = blockIdx.x * 256 + threadIdx.x;
  if (idx < 384*1152) {
    int k = idx / 1152, col = idx % 1152;
    float v;
    if (col < 192)      v = qw[(size_t)k*192 + col];
    else if (col < 576) v = kvw[(size_t)k*384 + (col-192)];
    else if (col < 720) v = qpw[(size_t)k*144 + (col-576)];
    else                v = kvpw[(size_t)k*432 + (col-720)];
    (ws + OFF_WPACK)[idx] = v;
  } else if (idx < 384*1152 + 1152) {
    int col = idx - 384*1152;
    float v;
    if (col < 192)      v = qb[col];
    else if (col < 576) v = kvb[col-192];
    else if (col < 720) v = qpb[col-576];
    else                v = kvpb[col-720];
    (ws + OFF_BPACK)[col] = v;
  }
}

// ---------------- K1: tiled projection GEMM 768x384 @ 384x1152 + bias -------
__global__ __launch_bounds__(256) void k1_proj(const float* __restrict__ x,
                                               float* __restrict__ ws) {
  int bi = blockIdx.x, bo = blockIdx.y, t = threadIdx.x;
  __shared__ float AsT[16*68];
  __shared__ float Bs[16*68];
  const float* W = ws + OFF_WPACK;
  float accv[4][4] = {};
  int i0 = bi*64, o0 = bo*64;
  int ti = t >> 4, to = t & 15;
  for (int kt = 0; kt < 24; kt++) {
    int k0 = kt*16;
    {
      int r = t >> 2, kq = t & 3;
      float4 a = *(const float4*)(x + (size_t)(i0+r)*C1V + k0 + kq*4);
      AsT[(kq*4+0)*68 + r] = a.x;
      AsT[(kq*4+1)*68 + r] = a.y;
      AsT[(kq*4+2)*68 + r] = a.z;
      AsT[(kq*4+3)*68 + r] = a.w;
      int kr = t >> 4, ol = t & 15;
      *(float4*)&Bs[kr*68 + ol*4] =
          *(const float4*)(W + (size_t)(k0+kr)*1152 + o0 + ol*4);
    }
    __syncthreads();
    for (int k = 0; k < 16; k++) {
      float4 a4 = *(float4*)&AsT[k*68 + ti*4];
      float4 b4 = *(float4*)&Bs[k*68 + to*4];
      accv[0][0] += a4.x*b4.x; accv[0][1] += a4.x*b4.y; accv[0][2] += a4.x*b4.z; accv[0][3] += a4.x*b4.w;
      accv[1][0] += a4.y*b4.x; accv[1][1] += a4.y*b4.y; accv[1][2] += a4.y*b4.z; accv[1][3] += a4.y*b4.w;
      accv[2][0] += a4.z*b4.x; accv[2][1] += a4.z*b4.y; accv[2][2] += a4.z*b4.z; accv[2][3] += a4.z*b4.w;
      accv[3][0] += a4.w*b4.x; accv[3][1] += a4.w*b4.y; accv[3][2] += a4.w*b4.z; accv[3][3] += a4.w*b4.w;
    }
    __syncthreads();
  }
  float* proj = ws + OFF_PROJ;
  const float* bp = ws + OFF_BPACK;
  #pragma unroll
  for (int ii = 0; ii < 4; ii++) {
    int orow = i0 + ti*4 + ii;
    int ocol = o0 + to*4;
    float4 bv = *(const float4*)(bp + ocol);
    float4 v = make_float4(accv[ii][0]+bv.x, accv[ii][1]+bv.y,
                           accv[ii][2]+bv.z, accv[ii][3]+bv.w);
    *(float4*)&proj[(size_t)orow*1152 + ocol] = v;
  }
}

// ---------------- K2: apply frames, build transposed V layouts --------------
__global__ __launch_bounds__(256) void k2_frames(float* __restrict__ ws) {
  int i = blockIdx.x, t = threadIdx.x;
  const float* R  = ws + OFF_R + (size_t)i*12;
  const float* tv = ws + OFF_T + (size_t)i*4;
  const float* prow = ws + OFF_PROJ + (size_t)i*1152;
  if (t < 144) {  // q points: d in [0,48), ci in [0,3)
    int d = t % 48, ci = t / 48;
    const float* qp = prow + 576;
    float v = R[ci*3+0]*qp[0*48+d] + R[ci*3+1]*qp[1*48+d] + R[ci*3+2]*qp[2*48+d] + tv[ci];
    int h = d / 4, p = d % 4;
    (ws + OFF_QPT)[(size_t)i*144 + h*12 + p*3 + ci] = v;
  }
  for (int r = 0; r < 2; r++) {  // kv points: 432 items
    int item = t + r*256;
    if (item < 432) {
      int d = item % 144, ci = item / 144;
      const float* kp = prow + 720;
      float v = R[ci*3+0]*kp[0*144+d] + R[ci*3+1]*kp[1*144+d] + R[ci*3+2]*kp[2*144+d] + tv[ci];
      int h = d / 12, pp = d % 12;
      if (pp < 4)
        (ws + OFF_KPT)[(size_t)i*144 + h*12 + pp*3 + ci] = v;
      else
        (ws + OFF_VPTT)[((size_t)(h*8 + (pp-4))*3 + ci)*768 + i] = v;
    }
  }
  if (t < 192) {  // v scalar transpose: [h*16+s][768]
    int h = t / 16, s = t % 16;
    (ws + OFF_VST)[(size_t)t*768 + i] = prow[192 + h*32 + 16 + s];
  }
}

// ---------------- K_att: fused flash attention (single rep pass) ------------
// One block per query i.  Wave w owns heads 3w..3w+2 for logits (lane = j).
// Online softmax; accumulators: att2d (lane=c-pair, wave=j-quarter),
// scalar/point V (thread-owned slots, transposed V rows).
__global__ __launch_bounds__(256) void k_att(const float* __restrict__ rep,
                                             const float* __restrict__ w2db_,
                                             float* __restrict__ ws) {
  __shared__ float tile[64*132];   // rep tile [jl][c], padded stride 132
  __shared__ float ptile[12*64];   // p values [h][jl]
  __shared__ float wds[12*128];    // w2d^T
  __shared__ float qsl[192], qptl[144];
  __shared__ float mrow[12], srow[12], frow[12], tmaxs[12], w2dbl[12], pwl[12];

  int i = blockIdx.x, t = threadIdx.x;
  int w = __builtin_amdgcn_readfirstlane(t >> 6);
  int lane = t & 63;

  // ---- init ----
  for (int u = t; u < 1536; u += 256) wds[u] = (ws + OFF_W2DT)[u];
  if (t < 192) qsl[t]  = (ws + OFF_PROJ)[(size_t)i*1152 + t];
  if (t < 144) qptl[t] = (ws + OFF_QPT)[(size_t)i*144 + t];
  if (t < 12) {
    mrow[t] = -1e30f; srow[t] = 0.f;
    pwl[t] = (ws + OFF_PW)[t];
    w2dbl[t] = w2db_[t];
  }
  float acc2d[12][2];
  #pragma unroll
  for (int h = 0; h < 12; h++) { acc2d[h][0] = 0.f; acc2d[h][1] = 0.f; }
  // V slots: slot0 = t (scalar if <192 else point), slot1 = t+256 (point, if <480)
  int h0, h1 = -1;
  const float* vrow0; const float* vrow1 = nullptr;
  if (t < 192) { h0 = t >> 4; vrow0 = ws + OFF_VST + (size_t)t*768; }
  else { int u = t - 192; h0 = u/24; vrow0 = ws + OFF_VPTT + (size_t)u*768; }
  if (t < 224) { int u = t + 64; h1 = u/24; vrow1 = ws + OFF_VPTT + (size_t)u*768; }
  float accV0 = 0.f, accV1 = 0.f;
  __syncthreads();

  const float sw  = 0.14433756729740643f;   // sqrt(1/48)
  const float c2d = 0.5773502691896258f;    // sqrt(1/3)

  for (int tt = 0; tt < 12; tt++) {
    int j0 = tt*64;
    // ---- stage rep tile ----
    #pragma unroll
    for (int k = 0; k < 8; k++) {
      int u = t + k*256;          // 2048 float4 chunks
      int row = u >> 5, c4 = u & 31;
      *(float4*)&tile[row*132 + c4*4] =
          *(const float4*)&rep[((size_t)i*768 + (j0+row))*128 + c4*4];
    }
    __syncthreads();

    // ---- logits for heads 3w..3w+2, j = j0+lane ----
    float a2d[3] = {0.f, 0.f, 0.f};
    for (int c4 = 0; c4 < 32; c4++) {
      float4 v = *(float4*)&tile[lane*132 + c4*4];
      #pragma unroll
      for (int hh = 0; hh < 3; hh++) {
        float4 wv = *(float4*)&wds[(w*3+hh)*128 + c4*4];
        a2d[hh] += v.x*wv.x + v.y*wv.y + v.z*wv.z + v.w*wv.w;
      }
    }
    int j = j0 + lane;
    const float* ksr  = ws + OFF_PROJ + (size_t)j*1152 + 192;
    const float* kptr = ws + OFF_KPT + (size_t)j*144;
    float l[3], tm[3];
    #pragma unroll
    for (int hh = 0; hh < 3; hh++) {
      int h = w*3 + hh;
      float ds_ = 0.f;
      #pragma unroll
      for (int s4 = 0; s4 < 4; s4++) {
        float4 q4 = *(const float4*)(qsl + h*16 + s4*4);
        float4 k4 = *(const float4*)(ksr + h*32 + s4*4);
        ds_ += q4.x*k4.x + q4.y*k4.y + q4.z*k4.z + q4.w*k4.w;
      }
      float dp = 0.f;
      #pragma unroll
      for (int pc = 0; pc < 3; pc++) {
        float4 q4 = *(const float4*)(qptl + h*12 + pc*4);
        float4 k4 = *(const float4*)(kptr + h*12 + pc*4);
        float dx = q4.x-k4.x, dy = q4.y-k4.y, dz = q4.z-k4.z, dw = q4.w-k4.w;
        dp += dx*dx + dy*dy + dz*dz + dw*dw;
      }
      l[hh] = sw*ds_ - 0.5f*pwl[h]*dp + c2d*(a2d[hh] + w2dbl[h]);
      float m = l[hh];
      #pragma unroll
      for (int d = 1; d < 64; d <<= 1) m = fmaxf(m, __shfl_xor(m, d));
      tm[hh] = m;
    }
    if (lane == 0) {
      tmaxs[w*3+0] = tm[0]; tmaxs[w*3+1] = tm[1]; tmaxs[w*3+2] = tm[2];
    }
    __syncthreads();

    // ---- running max update ----
    if (t < 12) {
      float mo = mrow[t];
      float mn = fmaxf(mo, tmaxs[t]);
      frow[t] = __expf(mo - mn);
      mrow[t] = mn;
    }
    __syncthreads();

    // ---- p = exp(l - m), running sum ----
    #pragma unroll
    for (int hh = 0; hh < 3; hh++) {
      int h = w*3 + hh;
      float p = __expf(l[hh] - mrow[h]);
      ptile[h*64 + lane] = p;
      float s = p;
      #pragma unroll
      for (int d = 1; d < 64; d <<= 1) s += __shfl_xor(s, d);
      if (lane == 0) srow[h] = srow[h]*frow[h] + s;
    }
    __syncthreads();

    // ---- accumulate ----
    // att2d: wave w owns jl in [w*16, w*16+16), lane owns c-pair lane*2
    #pragma unroll
    for (int h = 0; h < 12; h++) {
      float fh = frow[h];
      acc2d[h][0] *= fh; acc2d[h][1] *= fh;
    }
    int jb = w*16;
    for (int jj = 0; jj < 16; jj++) {
      int jl = jb + jj;
      float2 r2 = *(float2*)&tile[jl*132 + lane*2];
      #pragma unroll
      for (int h = 0; h < 12; h++) {
        float p = ptile[h*64 + jl];
        acc2d[h][0] += p*r2.x; acc2d[h][1] += p*r2.y;
      }
    }
    // V slots (full 64-j range, contiguous transposed V rows)
    {
      float a = accV0 * frow[h0];
      const float* vr = vrow0 + j0;
      for (int q = 0; q < 16; q++) {
        float4 v4 = *(const float4*)(vr + q*4);
        a += ptile[h0*64+q*4+0]*v4.x + ptile[h0*64+q*4+1]*v4.y
           + ptile[h0*64+q*4+2]*v4.z + ptile[h0*64+q*4+3]*v4.w;
      }
      accV0 = a;
    }
    if (h1 >= 0) {
      float a = accV1 * frow[h1];
      const float* vr = vrow1 + j0;
      for (int q = 0; q < 16; q++) {
        float4 v4 = *(const float4*)(vr + q*4);
        a += ptile[h1*64+q*4+0]*v4.x + ptile[h1*64+q*4+1]*v4.y
           + ptile[h1*64+q*4+2]*v4.z + ptile[h1*64+q*4+3]*v4.w;
      }
      accV1 = a;
    }
    __syncthreads();
  }

  // ---- epilogue ----
  float* fa = ws + OFF_FA + (size_t)i*2112;
  // V slots: normalize; scalar -> fa, points -> respt (alias ptile)
  float* respt = ptile;
  if (t < 192) fa[t] = accV0 / srow[h0];
  else respt[t - 192] = accV0 / srow[h0];
  if (h1 >= 0) respt[t + 64] = accV1 / srow[h1];
  // att2d partials -> redbuf (alias tile)
  float* redbuf = tile;
  #pragma unroll
  for (int h = 0; h < 12; h++) {
    redbuf[w*1536 + h*128 + lane*2 + 0] = acc2d[h][0];
    redbuf[w*1536 + h*128 + lane*2 + 1] = acc2d[h][1];
  }
  __syncthreads();
  // att2d reduce + normalize
  for (int r = 0; r < 6; r++) {
    int u = t + r*256;
    int h = u >> 7;
    float v = redbuf[u] + redbuf[1536+u] + redbuf[3072+u] + redbuf[4608+u];
    fa[576 + u] = v / srow[h];
  }
  // local frame transform + norms
  if (t < 96) {
    const float* R  = ws + OFF_R + (size_t)i*12;
    const float* tv = ws + OFF_T + (size_t)i*4;
    float g0 = respt[t*3+0] - tv[0];
    float g1 = respt[t*3+1] - tv[1];
    float g2 = respt[t*3+2] - tv[2];
    float l0 = R[0]*g0 + R[3]*g1 + R[6]*g2;   // R^T * g
    float l1 = R[1]*g0 + R[4]*g1 + R[7]*g2;
    float l2 = R[2]*g0 + R[5]*g1 + R[8]*g2;
    fa[192 + 0*96 + t] = l0;
    fa[192 + 1*96 + t] = l1;
    fa[192 + 2*96 + t] = l2;
    fa[480 + t] = sqrtf(1e-8f + l0*l0 + l1*l1 + l2*l2);
  }
}

// ---------------- K7: final GEMM 768x2112 @ 2112x384, split-K=4 -------------
__global__ __launch_bounds__(256) void k7_gemm(const float* __restrict__ finw,
                                               float* __restrict__ ws) {
  int bi = blockIdx.x, bo = blockIdx.y, bz = blockIdx.z, t = threadIdx.x;
  __shared__ float AsT[16*68];
  __shared__ float Bs[16*68];
  const float* fa = ws + OFF_FA;
  float accv[4][4] = {};
  int i0 = bi*64, o0 = bo*64;
  int ti = t >> 4, to = t & 15;
  for (int kt = 0; kt < 33; kt++) {
    int k0 = bz*528 + kt*16;
    {
      int r = t >> 2, kq = t & 3;
      float4 a = *(const float4*)(fa + (size_t)(i0+r)*2112 + k0 + kq*4);
      AsT[(kq*4+0)*68 + r] = a.x;
      AsT[(kq*4+1)*68 + r] = a.y;
      AsT[(kq*4+2)*68 + r] = a.z;
      AsT[(kq*4+3)*68 + r] = a.w;
      int kr = t >> 4, ol = t & 15;
      *(float4*)&Bs[kr*68 + ol*4] =
          *(const float4*)(finw + (size_t)(k0+kr)*384 + o0 + ol*4);
    }
    __syncthreads();
    for (int k = 0; k < 16; k++) {
      float4 a4 = *(float4*)&AsT[k*68 + ti*4];
      float4 b4 = *(float4*)&Bs[k*68 + to*4];
      accv[0][0] += a4.x*b4.x; accv[0][1] += a4.x*b4.y; accv[0][2] += a4.x*b4.z; accv[0][3] += a4.x*b4.w;
      accv[1][0] += a4.y*b4.x; accv[1][1] += a4.y*b4.y; accv[1][2] += a4.y*b4.z; accv[1][3] += a4.y*b4.w;
      accv[2][0] += a4.z*b4.x; accv[2][1] += a4.z*b4.y; accv[2][2] += a4.z*b4.z; accv[2][3] += a4.z*b4.w;
      accv[3][0] += a4.w*b4.x; accv[3][1] += a4.w*b4.y; accv[3][2] += a4.w*b4.z; accv[3][3] += a4.w*b4.w;
    }
    __syncthreads();
  }
  float* part = ws + OFF_PART + (size_t)bz*768*384;
  #pragma unroll
  for (int ii = 0; ii < 4; ii++) {
    float4 v = make_float4(accv[ii][0], accv[ii][1], accv[ii][2], accv[ii][3]);
    *(float4*)&part[(size_t)(i0 + ti*4 + ii)*384 + o0 + to*4] = v;
  }
}

// ---------------- K8: split-K reduce + bias ---------------------------------
__global__ void k8_out(const float* __restrict__ finb,
                       const float* __restrict__ ws,
                       float* __restrict__ out) {
  int idx = blockIdx.x*256 + threadIdx.x;  // 294912
  int o = idx % 384;
  const float* part = ws + OFF_PART;
  out[idx] = part[idx] + part[294912 + idx] + part[2*294912 + idx]
           + part[3*294912 + idx] + finb[o];
}

// ---------------------------------------------------------------------------
extern "C" void kernel_launch(void* const* d_in, const int* in_sizes, int n_in,
                              void* d_out, int out_size, void* d_ws, size_t ws_size,
                              hipStream_t stream) {
  const float* rec1d = (const float*)d_in[0];
  const float* rep2d = (const float*)d_in[1];
  const float* recT  = (const float*)d_in[2];
  const float* qw    = (const float*)d_in[3];
  const float* qb    = (const float*)d_in[4];
  const float* kvw   = (const float*)d_in[5];
  const float* kvb   = (const float*)d_in[6];
  const float* qpw   = (const float*)d_in[7];
  const float* qpb   = (const float*)d_in[8];
  const float* kvpw  = (const float*)d_in[9];
  const float* kvpb  = (const float*)d_in[10];
  const float* w2dw  = (const float*)d_in[11];
  const float* w2db  = (const float*)d_in[12];
  const float* finw  = (const float*)d_in[13];
  const float* finb  = (const float*)d_in[14];
  const float* tw    = (const float*)d_in[15];
  float* ws  = (float*)d_ws;
  float* out = (float*)d_out;

  hipLaunchKernelGGL(k0_prep, dim3(10), dim3(256), 0, stream, recT, tw, w2dw, ws);
  hipLaunchKernelGGL(k0b_pack, dim3(1733), dim3(256), 0, stream,
                     qw, qb, kvw, kvb, qpw, qpb, kvpw, kvpb, ws);
  hipLaunchKernelGGL(k1_proj, dim3(12, 18), dim3(256), 0, stream, rec1d, ws);
  hipLaunchKernelGGL(k2_frames, dim3(768), dim3(256), 0, stream, ws);
  hipLaunchKernelGGL(k_att, dim3(768), dim3(256), 0, stream, rep2d, w2db, ws);
  hipLaunchKernelGGL(k7_gemm, dim3(12, 6, 4), dim3(256), 0, stream, finw, ws);
  hipLaunchKernelGGL(k8_out, dim3(1152), dim3(256), 0, stream, finb, ws, out);
}